// Round 8
// baseline (8727.817 us; speedup 1.0000x reference)
//
#include <hip/hip_runtime.h>

#define T_SEQ 2048
#define HDIM  128
#define GDIM  512
#define BATCH 256

// FIFO: per batch element, DEPTH slots of (512 xg f32 + 64 h0hi f32)
#define DEPTH    32
#define SLOT_DW  576
#define FLAGS_DW 8192   // prod[b*16] | cons at +4096
#define WS_NEED  ((size_t)(FLAGS_DW + (size_t)BATCH * DEPTH * SLOT_DW) * 4)

typedef _Float16 f16;
typedef _Float16 f16x2 __attribute__((ext_vector_type(2)));
typedef _Float16 f16x8 __attribute__((ext_vector_type(8)));

#if __has_builtin(__builtin_amdgcn_fdot2)
__device__ __forceinline__ float dot2(f16x2 a, f16x2 b, float c) {
    return __builtin_amdgcn_fdot2(a, b, c, false);
}
#else
__device__ __forceinline__ float dot2(f16x2 a, f16x2 b, float c) {
    return c + (float)a[0] * (float)b[0] + (float)a[1] * (float)b[1];
}
#endif

__device__ __forceinline__ f16x2 mk2(float a, float b) {
    f16x2 r; r[0] = (f16)a; r[1] = (f16)b; return r;
}
__device__ __forceinline__ f16x2 pr(f16x8 v, int m) {
    f16x2 r; r[0] = v[2 * m]; r[1] = v[2 * m + 1]; return r;
}
__device__ __forceinline__ float sigm(float x) {
    return __builtin_amdgcn_rcpf(1.0f + __expf(-x));
}
__device__ __forceinline__ float tanh_fast(float x) {
    float e = __expf(2.0f * x);
    return 1.0f - 2.0f * __builtin_amdgcn_rcpf(e + 1.0f);
}

// Device-scope (L2-bypassing, cross-XCD-coherent) loads/stores. These are
// plain ld/st with sc bits, not RMW atomics -> full streaming rate via L3.
__device__ __forceinline__ uint ldv(const uint* p) {
    return __hip_atomic_load(p, __ATOMIC_RELAXED, __HIP_MEMORY_SCOPE_AGENT);
}
__device__ __forceinline__ void stv(uint* p, uint v) {
    __hip_atomic_store(p, v, __ATOMIC_RELAXED, __HIP_MEMORY_SCOPE_AGENT);
}

// ===== producer/consumer fused LSTM =====
// Rounds 0-7 law: reg grant = 1024/(waves per block); the fused scan needs
// 192 weight dw/thread but only 96 fit cleanly -> one block cannot hold it.
// Split per batch element into TWO 512-thread blocks, both 96 weight dw
// (round-5-proven spill-free), running CONCURRENTLY:
//   role 0 (layer0): regs = Whh0 row (64 dw) + Wih1[:,0:64] (32 dw).
//     Per step publishes slot i = { xg_i = b1 + Wih1lo.h0lo(i) ; h0hi(i) }.
//   role 1 (layer1): regs = Whh1 row (64 dw) + Wih1[:,64:128] (32 dw).
//     Per step consumes slot j (prefetched 1 step ahead, L3 latency hidden).
// grid = 512 = 2 blocks/CU exactly (128 VGPR x 4 waves/SIMD = full file),
// so all blocks are co-resident -> spin-waits cannot deadlock.
// Ordering: producer drains its stores (per-wave vmcnt(0) + barrier) one
// full iteration before release-publishing prod; consumer's data loads are
// execution-ordered behind the acquire-spin via __syncthreads.
// Flow control: DEPTH=32 slots; producer blocks at cons+30, consumer at
// prod-3 -> lag self-stabilizes in (4,30); steady state is spin-free.
__global__ __launch_bounds__(512, 2)
void lstm_pc(const float* __restrict__ x,
             const float* __restrict__ Wih0,
             const float* __restrict__ Whh0,
             const float* __restrict__ bih0,
             const float* __restrict__ bhh0,
             const float* __restrict__ Wih1,
             const float* __restrict__ Whh1,
             const float* __restrict__ bih1,
             const float* __restrict__ bhh1,
             const float* __restrict__ Wfc,
             const float* __restrict__ bfc,
             uint* __restrict__ ws,
             float* __restrict__ out)
{
    __shared__ __align__(16) float xs[T_SEQ];   // role0: x[b,:] (8 KB)
    __shared__ __align__(16) f16   hsh[HDIM];   // own-layer h state (f16)
    __shared__ float hsf[HDIM];                 // f32 copy for outputs
    __shared__ float g[GDIM];                   // gate preactivations
    __shared__ __align__(16) f16   hh[2][64];   // role1: h0hi double buffer

    const int t    = threadIdx.x;
    const int b    = blockIdx.x >> 1;
    const int role = blockIdx.x & 1;
    uint* prod = ws + b * 16;
    uint* cons = ws + 4096 + b * 16;
    uint* fif  = ws + FLAGS_DW + (size_t)b * (DEPTH * SLOT_DW);

    float cr = 0.f;                             // cell state (update threads)
    if (t < HDIM) { hsh[t] = (f16)0.f; hsf[t] = 0.f; }

    if (role == 0) {
        // ================= layer-0 producer =================
        ((float4*)xs)[t] = ((const float4*)(x + (size_t)b * T_SEQ))[t];
        f16x2 wa[64];  // Whh0[t, 0:128]
        f16x2 wb[32];  // Wih1[t, 0:64]
        {
            const float4* pa = (const float4*)(Whh0 + t * HDIM);
            const float4* pb = (const float4*)(Wih1 + t * HDIM);
#pragma unroll
            for (int c = 0; c < 32; ++c) {
                float4 v = pa[c];
                wa[2*c]   = mk2(v.x, v.y);
                wa[2*c+1] = mk2(v.z, v.w);
            }
#pragma unroll
            for (int c = 0; c < 16; ++c) {
                float4 v = pb[c];
                wb[2*c]   = mk2(v.x, v.y);
                wb[2*c+1] = mk2(v.z, v.w);
            }
        }
        const float wx0   = Wih0[t];
        const float bias0 = bih0[t] + bhh0[t];
        const float b1    = bih1[t] + bhh1[t];   // layer1 bias rides in xg
        const f16x8* hp = (const f16x8*)hsh;
        int consv = 0;

        for (int i = 0; i <= T_SEQ; ++i) {
            // drain ALL waves' fifo stores from iter i-1, then publish.
            asm volatile("s_waitcnt vmcnt(0)" ::: "memory");
            __syncthreads();
            if (t == 0) {
                if (i >= 2)
                    __hip_atomic_store(prod, (uint)(i - 1), __ATOMIC_RELEASE,
                                       __HIP_MEMORY_SCOPE_AGENT);
                if (consv < i - 30)                       // slot-reuse gate
                    do { consv = (int)ldv(cons); } while (consv < i - 30);
            }
            float s0a = (i < T_SEQ ? xs[i] : 0.f) * wx0 + bias0;
            float s0b = 0.f, s0c = 0.f, s0d = 0.f;
            float s1a = b1, s1b = 0.f;
#pragma unroll
            for (int c = 0; c < 16; ++c) {
                f16x8 h = hp[c];
                s0a = dot2(wa[4*c+0], pr(h,0), s0a);
                s0b = dot2(wa[4*c+1], pr(h,1), s0b);
                s0c = dot2(wa[4*c+2], pr(h,2), s0c);
                s0d = dot2(wa[4*c+3], pr(h,3), s0d);
                if (c < 8) {                    // k=0..63 layer1 input partial
                    s1a = dot2(wb[4*c+0], pr(h,0), s1a);
                    s1b = dot2(wb[4*c+1], pr(h,1), s1b);
                    s1a = dot2(wb[4*c+2], pr(h,2), s1a);
                    s1b = dot2(wb[4*c+3], pr(h,3), s1b);
                }
            }
            if (i >= 1)
                stv(&fif[((i-1) & (DEPTH-1)) * SLOT_DW + t],
                    __float_as_uint(s1a + s1b));
            if (i < T_SEQ) g[t] = (s0a + s0b) + (s0c + s0d);
            __syncthreads();
            if (t < 128 && i < T_SEQ) {
                float gi = sigm(g[t]);
                float gf = sigm(g[t + 128]);
                float gg = tanh_fast(g[t + 256]);
                float go = sigm(g[t + 384]);
                cr = gf * cr + gi * gg;
                float h = go * tanh_fast(cr);
                hsh[t] = (f16)h; hsf[t] = h;
                if (t >= 64)                     // publish h0 high half (f32)
                    stv(&fif[(i & (DEPTH-1)) * SLOT_DW + 512 + (t - 64)],
                        __float_as_uint(h));
            }
            __syncthreads();
        }
        asm volatile("s_waitcnt vmcnt(0)" ::: "memory");
        __syncthreads();
        if (t == 0)
            __hip_atomic_store(prod, (uint)T_SEQ, __ATOMIC_RELEASE,
                               __HIP_MEMORY_SCOPE_AGENT);
        if (t < 128) {
            out[BATCH + (size_t)b * HDIM + t] = hsf[t];
            out[BATCH + 2 * BATCH * HDIM + (size_t)b * HDIM + t] = cr;
        }
    } else {
        // ================= layer-1 consumer =================
        f16x2 wa[64];  // Whh1[t, 0:128]
        f16x2 wb[32];  // Wih1[t, 64:128]
        {
            const float4* pa = (const float4*)(Whh1 + t * HDIM);
            const float4* pb = (const float4*)(Wih1 + t * HDIM + 64);
#pragma unroll
            for (int c = 0; c < 32; ++c) {
                float4 v = pa[c];
                wa[2*c]   = mk2(v.x, v.y);
                wa[2*c+1] = mk2(v.z, v.w);
            }
#pragma unroll
            for (int c = 0; c < 16; ++c) {
                float4 v = pb[c];
                wb[2*c]   = mk2(v.x, v.y);
                wb[2*c+1] = mk2(v.z, v.w);
            }
        }
        int pc = 0;
        if (t == 501) {                         // wait for slots 0,1
            do {
                pc = (int)__hip_atomic_load(prod, __ATOMIC_ACQUIRE,
                                            __HIP_MEMORY_SCOPE_AGENT);
            } while (pc < 2);
        }
        __syncthreads();
        uint xgc = ldv(&fif[t]);                // slot 0 xg
        if (t >= 448)
            hh[0][t - 448] = (f16)__uint_as_float(ldv(&fif[512 + (t - 448)]));
        __syncthreads();
        const f16x8* hp = (const f16x8*)hsh;    // h1 state

        for (int j = 0; j < T_SEQ; ++j) {
            // prefetch slot j+1 (valid: prod >= j+2 was ensured last step)
            uint xgn = 0u; float hnv = 0.f;
            if (j + 1 < T_SEQ) {
                const int s = ((j + 1) & (DEPTH - 1)) * SLOT_DW;
                xgn = ldv(&fif[s + t]);
                if (t >= 448)
                    hnv = __uint_as_float(ldv(&fif[s + 512 + (t - 448)]));
            }
            const f16x8* hx = (const f16x8*)hh[j & 1];
            float s1a = __uint_as_float(xgc), s1b = 0.f, s1c = 0.f, s1d = 0.f;
#pragma unroll
            for (int c = 0; c < 16; ++c) {
                f16x8 h = hp[c];
                s1a = dot2(wa[4*c+0], pr(h,0), s1a);
                s1b = dot2(wa[4*c+1], pr(h,1), s1b);
                s1c = dot2(wa[4*c+2], pr(h,2), s1c);
                s1d = dot2(wa[4*c+3], pr(h,3), s1d);
                if (c < 8) {                    // Wih1 high x h0hi
                    f16x8 hq = hx[c];
                    s1c = dot2(wb[4*c+0], pr(hq,0), s1c);
                    s1d = dot2(wb[4*c+1], pr(hq,1), s1d);
                    s1c = dot2(wb[4*c+2], pr(hq,2), s1c);
                    s1d = dot2(wb[4*c+3], pr(hq,3), s1d);
                }
            }
            g[t] = (s1a + s1b) + (s1c + s1d);
            __syncthreads();
            if (t < 128) {
                float gi = sigm(g[t]);
                float gf = sigm(g[t + 128]);
                float gg = tanh_fast(g[t + 256]);
                float go = sigm(g[t + 384]);
                cr = gf * cr + gi * gg;
                float h = go * tanh_fast(cr);
                hsh[t] = (f16)h; hsf[t] = h;
            } else if (t >= 448) {
                hh[(j + 1) & 1][t - 448] = (f16)hnv;   // stage next h0hi
            }
            if (t == 500) stv(cons, (uint)(j + 1));    // progress (every step)
            if (t == 501) {                            // ensure prod >= j+3
                int need = j + 3; if (need > T_SEQ) need = T_SEQ;
                if (pc < need) {
                    do {
                        pc = (int)__hip_atomic_load(prod, __ATOMIC_ACQUIRE,
                                                    __HIP_MEMORY_SCOPE_AGENT);
                    } while (pc < need);
                }
            }
            __syncthreads();
            xgc = xgn;
        }
        if (t < 128) {
            out[BATCH + BATCH * HDIM + (size_t)b * HDIM + t] = hsf[t];
            out[BATCH + 2 * BATCH * HDIM + BATCH * HDIM + (size_t)b * HDIM + t] = cr;
        }
        if (t < 64) {
            float p = hsf[t] * Wfc[t] + hsf[t + 64] * Wfc[t + 64];
#pragma unroll
            for (int o = 32; o >= 1; o >>= 1) p += __shfl_down(p, o);
            if (t == 0) out[b] = p + bfc[0];
        }
    }
}

// ======== fallback (workspace too small) — round-2 kernel, verified ========
__global__ __launch_bounds__(1024)
void lstm_fused_fb(const float* __restrict__ x,
                   const float* __restrict__ Wih0,
                   const float* __restrict__ Whh0,
                   const float* __restrict__ bih0,
                   const float* __restrict__ bhh0,
                   const float* __restrict__ Wih1,
                   const float* __restrict__ Whh1,
                   const float* __restrict__ bih1,
                   const float* __restrict__ bhh1,
                   const float* __restrict__ Wfc,
                   const float* __restrict__ bfc,
                   float* __restrict__ out)
{
    __shared__ __align__(16) float xs[T_SEQ];
    __shared__ __align__(16) f16   h0h[HDIM];
    __shared__ __align__(16) f16   h1h[HDIM];
    __shared__ float h0f[HDIM], h1f[HDIM];
    __shared__ float g0[GDIM];
    __shared__ float g1a[GDIM], g1b[GDIM];

    const int t  = threadIdx.x;
    const int b  = blockIdx.x;
    const bool gA = (t < 512);
    const int r  = t & 511;

    if (gA)
        ((float4*)xs)[t] = ((const float4*)(x + (size_t)b * T_SEQ))[t];

    f16x2 wa[64];
    f16x2 wb[32];
    {
        const float4* pa = (const float4*)((gA ? Whh0 : Wih1) + r * HDIM);
        const float4* pb = (const float4*)(Whh1 + r * HDIM + (gA ? 0 : 64));
#pragma unroll
        for (int c = 0; c < 32; ++c) {
            float4 v = pa[c];
            wa[2*c]   = mk2(v.x, v.y);
            wa[2*c+1] = mk2(v.z, v.w);
        }
#pragma unroll
        for (int c = 0; c < 16; ++c) {
            float4 v = pb[c];
            wb[2*c]   = mk2(v.x, v.y);
            wb[2*c+1] = mk2(v.z, v.w);
        }
    }
    const float xw   = gA ? Wih0[r] : 0.f;
    const float bias = gA ? (bih0[r] + bhh0[r]) : (bih1[r] + bhh1[r]);

    if (t < HDIM) {
        h0h[t] = (f16)0.f; h1h[t] = (f16)0.f;
        h0f[t] = 0.f;      h1f[t] = 0.f;
    }
    float c0r = 0.f, c1r = 0.f;
    __syncthreads();

    const f16x8* h0p  = (const f16x8*)h0h;
    const f16x8* hsel = ((const f16x8*)h1h) + (gA ? 0 : 8);

    for (int i = 0; i <= T_SEQ; ++i) {
        float sa = (i < T_SEQ ? xs[i] : 0.f) * xw + bias;
        float sb = 0.f, sc = 0.f, sd = 0.f;
#pragma unroll
        for (int c = 0; c < 16; ++c) {
            f16x8 h = h0p[c];
            sa = dot2(wa[4*c+0], pr(h,0), sa);
            sb = dot2(wa[4*c+1], pr(h,1), sb);
            sa = dot2(wa[4*c+2], pr(h,2), sa);
            sb = dot2(wa[4*c+3], pr(h,3), sb);
        }
#pragma unroll
        for (int c = 0; c < 8; ++c) {
            f16x8 h = hsel[c];
            sc = dot2(wb[4*c+0], pr(h,0), sc);
            sd = dot2(wb[4*c+1], pr(h,1), sd);
            sc = dot2(wb[4*c+2], pr(h,2), sc);
            sd = dot2(wb[4*c+3], pr(h,3), sd);
        }
        if (gA) { g0[r] = sa + sb; g1a[r] = sc + sd; }
        else    { g1b[r] = (sa + sb) + (sc + sd); }
        __syncthreads();

        if (t < 128) {
            if (i < T_SEQ) {
                float gi = sigm(g0[t]);
                float gf = sigm(g0[t + 128]);
                float gg = tanh_fast(g0[t + 256]);
                float go = sigm(g0[t + 384]);
                c0r = gf * c0r + gi * gg;
                float h = go * tanh_fast(c0r);
                h0h[t] = (f16)h;
                h0f[t] = h;
            }
        } else if (t >= 512 && t < 640) {
            if (i >= 1) {
                int j = t - 512;
                float gi = sigm(g1a[j]       + g1b[j]);
                float gf = sigm(g1a[j + 128] + g1b[j + 128]);
                float gg = tanh_fast(g1a[j + 256] + g1b[j + 256]);
                float go = sigm(g1a[j + 384] + g1b[j + 384]);
                c1r = gf * c1r + gi * gg;
                float h = go * tanh_fast(c1r);
                h1h[j] = (f16)h;
                h1f[j] = h;
            }
        }
        __syncthreads();
    }

    float* hn = out + BATCH;
    float* cn = out + BATCH + 2 * BATCH * HDIM;
    if (t < 128) {
        hn[(size_t)b * HDIM + t] = h0f[t];
        cn[(size_t)b * HDIM + t] = c0r;
    } else if (t >= 512 && t < 640) {
        int j = t - 512;
        hn[BATCH * HDIM + (size_t)b * HDIM + j] = h1f[j];
        cn[BATCH * HDIM + (size_t)b * HDIM + j] = c1r;
    }
    if (t < 64) {
        float p = h1f[t] * Wfc[t] + h1f[t + 64] * Wfc[t + 64];
#pragma unroll
        for (int o = 32; o >= 1; o >>= 1) p += __shfl_down(p, o);
        if (t == 0) out[b] = p + bfc[0];
    }
}

extern "C" void kernel_launch(void* const* d_in, const int* in_sizes, int n_in,
                              void* d_out, int out_size, void* d_ws, size_t ws_size,
                              hipStream_t stream) {
    const float* x    = (const float*)d_in[0];
    const float* Wih0 = (const float*)d_in[1];
    const float* Whh0 = (const float*)d_in[2];
    const float* bih0 = (const float*)d_in[3];
    const float* bhh0 = (const float*)d_in[4];
    const float* Wih1 = (const float*)d_in[5];
    const float* Whh1 = (const float*)d_in[6];
    const float* bih1 = (const float*)d_in[7];
    const float* bhh1 = (const float*)d_in[8];
    const float* Wfc  = (const float*)d_in[9];
    const float* bfc  = (const float*)d_in[10];
    float* out = (float*)d_out;

    if (d_ws && ws_size >= WS_NEED) {
        hipMemsetAsync(d_ws, 0, FLAGS_DW * 4, stream);   // reset prod/cons
        lstm_pc<<<2 * BATCH, GDIM, 0, stream>>>(x, Wih0, Whh0, bih0, bhh0,
                                                Wih1, Whh1, bih1, bhh1,
                                                Wfc, bfc, (uint*)d_ws, out);
    } else {
        lstm_fused_fb<<<BATCH, 1024, 0, stream>>>(x, Wih0, Whh0, bih0, bhh0,
                                                  Wih1, Whh1, bih1, bhh1,
                                                  Wfc, bfc, out);
    }
}